// Round 3
// 551.862 us; speedup vs baseline: 1.0457x; 1.0457x over previous
//
#include <hip/hip_runtime.h>

typedef __attribute__((ext_vector_type(8))) short s8v;
typedef __attribute__((ext_vector_type(4))) short s4v;
typedef __attribute__((ext_vector_type(4))) float f4v;

__device__ __forceinline__ unsigned short f2bf(float f) {
  unsigned int u = __float_as_uint(f);
  u += 0x7FFFu + ((u >> 16) & 1u);   // RNE
  return (unsigned short)(u >> 16);
}
__device__ __forceinline__ float bf2f(unsigned short s) {
  return __uint_as_float(((unsigned int)s) << 16);
}

// async global->LDS 16B: lane i deposits at wave-uniform base + i*16
__device__ __forceinline__ void gld16(const void* g, void* l) {
  __builtin_amdgcn_global_load_lds(
      (const __attribute__((address_space(1))) unsigned int*)g,
      (__attribute__((address_space(3))) unsigned int*)l, 16, 0, 0);
}

// fused per-tile handoff: drain this wave's async loads + LDS ops, then barrier.
// asm block with memory clobber so no LDS access is scheduled across it.
#define TILE_SYNC() asm volatile("s_waitcnt vmcnt(0) lgkmcnt(0)\n\ts_barrier" ::: "memory")

// ---------------------------------------------------------------------------
// Pass 0a: X fp32 [65536,512] -> Xbf bf16.
// ---------------------------------------------------------------------------
__global__ __launch_bounds__(256)
void convert_x_kernel(const float* __restrict__ X, unsigned short* __restrict__ Xbf)
{
  size_t base = ((size_t)blockIdx.x * 256 + threadIdx.x) * 8;
  float4 a = *(const float4*)&X[base];
  float4 b = *(const float4*)&X[base + 4];
  s8v p = (s8v){ (short)f2bf(a.x), (short)f2bf(a.y), (short)f2bf(a.z), (short)f2bf(a.w),
                 (short)f2bf(b.x), (short)f2bf(b.y), (short)f2bf(b.z), (short)f2bf(b.w) };
  *(s8v*)&Xbf[base] = p;
}

// ---------------------------------------------------------------------------
// Pass 0b: Wt[n][k] bf16, n = 0..511 Wq | 512..1023 Wk | 1024..1535 Wv.
// ---------------------------------------------------------------------------
__global__ __launch_bounds__(256)
void transpose_w_kernel(const float* __restrict__ Wq, const float* __restrict__ Wk,
                        const float* __restrict__ Wv, unsigned short* __restrict__ Wt)
{
  __shared__ float T[64][68];
  const int kt = blockIdx.x, nt = blockIdx.y;
  const float* W = (nt < 8) ? Wq : (nt < 16 ? Wk : Wv);
  const int n0 = (nt & 7) * 64, k0 = kt * 64;
  const int t = threadIdx.x;
  #pragma unroll
  for (int it = 0; it < 4; ++it) {
    int idx = it * 256 + t;
    int k = idx >> 4, n4 = (idx & 15) << 2;
    *(float4*)&T[k][n4] = *(const float4*)&W[(size_t)(k0 + k) * 512 + n0 + n4];
  }
  __syncthreads();
  #pragma unroll
  for (int it = 0; it < 2; ++it) {
    int idx = it * 256 + t;
    int n = idx >> 3, k8 = (idx & 7) << 3;
    s8v p;
    #pragma unroll
    for (int j = 0; j < 8; ++j) p[j] = (short)f2bf(T[k8 + j][n]);
    *(s8v*)&Wt[((size_t)nt * 64 + n) * 512 + k0 + k8] = p;
  }
}

// ---------------------------------------------------------------------------
// GEMM1: qkv = Xbf @ Wt^T (+bias), q-part normalized per head * gamma.
// 128x128 tile, 4 waves (proven mapping), now 2-phase double-buffered:
//   prologue: stage tile0; TILE_SYNC
//   loop:     issue stage(tile t+1 -> buf^1)  [vmcnt stays in flight]
//             ds_read + 32 MFMA on buf        [hides the load latency]
//             TILE_SYNC (vmcnt0+lgkm0+barrier, once per tile)
// vs old stage->drain->compute: the HBM/L2 latency now overlaps compute.
// XCD-bijective swizzle on a 1D 6144 grid: each XCD owns 768 contiguous swz
// (64 rb-rows x all 12 nb, nb fast) -> A-panel read once per XCD, B (1.5 MB)
// L2-resident.
// ---------------------------------------------------------------------------
__global__ __launch_bounds__(256, 2)
void gemm_qkv_kernel(const unsigned short* __restrict__ Xbf,
                     const unsigned short* __restrict__ Wt,
                     const float* __restrict__ bq, const float* __restrict__ bk,
                     const float* __restrict__ bv,
                     const float* __restrict__ gamma,
                     unsigned short* __restrict__ qkv)
{
  __shared__ short As[2][8192];   // 2 x 16 KB (128 rows x 64 cols bf16)
  __shared__ short Bs[2][8192];
  const int t = threadIdx.x;
  const int o = blockIdx.x;                    // 6144 blocks
  const int swz = (o & 7) * 768 + (o >> 3);    // bijective XCD swizzle
  const int nb = swz % 12, rb = swz / 12;      // nb fast within XCD chunk
  const int wave = t >> 6, lane = t & 63;
  const int wm = wave & 1, wn = wave >> 1;
  const int quad = lane >> 4, l16 = lane & 15;
  const int row0 = rb * 128;
  const int ncol0 = nb * 128;

  // staging pointers: 4 granule slots per thread for each of A,B
  const unsigned short* ap[4];
  const unsigned short* bp[4];
  int ldst[4];
  #pragma unroll
  for (int i = 0; i < 4; ++i) {
    int s = i * 256 + t;
    int m = s >> 3;
    int kb = (s & 7) ^ (m & 7);
    ap[i] = Xbf + (size_t)(row0 + m) * 512 + kb * 8;
    bp[i] = Wt + (size_t)(ncol0 + m) * 512 + kb * 8;
    ldst[i] = s * 8;
  }

  f4v acc[4][4];
  #pragma unroll
  for (int i = 0; i < 4; ++i)
    #pragma unroll
    for (int j = 0; j < 4; ++j) acc[i][j] = (f4v){0.f, 0.f, 0.f, 0.f};

  // prologue: stage tile 0 into buffer 0
  #pragma unroll
  for (int i = 0; i < 4; ++i) {
    gld16(ap[i], &As[0][ldst[i]]);
    gld16(bp[i], &Bs[0][ldst[i]]);
  }
  TILE_SYNC();

  for (int kt = 0; kt < 8; ++kt) {
    const int cur = kt & 1;
    // issue next-tile stage first (loads in flight across the compute phase)
    if (kt < 7) {
      const int koff = (kt + 1) * 64;
      #pragma unroll
      for (int i = 0; i < 4; ++i) {
        gld16(ap[i] + koff, &As[cur ^ 1][ldst[i]]);
        gld16(bp[i] + koff, &Bs[cur ^ 1][ldst[i]]);
      }
    }
    // compute on current buffer
    #pragma unroll
    for (int ks = 0; ks < 2; ++ks) {
      s8v a[4], b[4];
      #pragma unroll
      for (int mi = 0; mi < 4; ++mi) {
        int r = wm * 64 + mi * 16 + l16;
        int slot = r * 8 + ((ks * 4 + quad) ^ (r & 7));
        a[mi] = *(const s8v*)&As[cur][slot * 8];
      }
      #pragma unroll
      for (int nj = 0; nj < 4; ++nj) {
        int r = wn * 64 + nj * 16 + l16;
        int slot = r * 8 + ((ks * 4 + quad) ^ (r & 7));
        b[nj] = *(const s8v*)&Bs[cur][slot * 8];
      }
      #pragma unroll
      for (int mi = 0; mi < 4; ++mi)
        #pragma unroll
        for (int nj = 0; nj < 4; ++nj)
          acc[mi][nj] = __builtin_amdgcn_mfma_f32_16x16x32_bf16(a[mi], b[nj], acc[mi][nj], 0, 0, 0);
    }
    TILE_SYNC();
  }

  // bias (zeros here, kept for semantics)
  #pragma unroll
  for (int nj = 0; nj < 4; ++nj) {
    int colg = ncol0 + wn * 64 + nj * 16 + l16;
    float bias;
    if (colg < 512) bias = bq[colg];
    else if (colg < 1024) bias = bk[colg - 512];
    else bias = bv[colg - 1024];
    #pragma unroll
    for (int mi = 0; mi < 4; ++mi) {
      acc[mi][nj][0] += bias; acc[mi][nj][1] += bias;
      acc[mi][nj][2] += bias; acc[mi][nj][3] += bias;
    }
  }

  // fused q-normalization: wave's 64 cols == one head; norm over DK=64 per row
  if (nb < 4) {
    float g = gamma[nb * 2 + wn];
    #pragma unroll
    for (int mi = 0; mi < 4; ++mi)
      #pragma unroll
      for (int rr = 0; rr < 4; ++rr) {
        float ss = acc[mi][0][rr] * acc[mi][0][rr] + acc[mi][1][rr] * acc[mi][1][rr]
                 + acc[mi][2][rr] * acc[mi][2][rr] + acc[mi][3][rr] * acc[mi][3][rr];
        ss += __shfl_xor(ss, 1);
        ss += __shfl_xor(ss, 2);
        ss += __shfl_xor(ss, 4);
        ss += __shfl_xor(ss, 8);
        float scale = g * rsqrtf(ss);
        acc[mi][0][rr] *= scale; acc[mi][1][rr] *= scale;
        acc[mi][2][rr] *= scale; acc[mi][3][rr] *= scale;
      }
  }

  const int colbase = ncol0 + wn * 64;
  #pragma unroll
  for (int mi = 0; mi < 4; ++mi)
    #pragma unroll
    for (int nj = 0; nj < 4; ++nj)
      #pragma unroll
      for (int rr = 0; rr < 4; ++rr) {
        int row = row0 + wm * 64 + mi * 16 + quad * 4 + rr;
        int col = colbase + nj * 16 + l16;
        qkv[(size_t)row * 1536 + col] = f2bf(acc[mi][nj][rr]);
      }
}

// ---------------------------------------------------------------------------
// kv partials: per (bh, chunk of 512 rows). 8x8 per lane, waves split rows.
// 64 partial slices (chunk*4+wave), no atomics.
// ---------------------------------------------------------------------------
__global__ __launch_bounds__(256)
void kv_accum_kernel(const unsigned short* __restrict__ qkv, float* __restrict__ kvpart)
{
  __shared__ float ksf[16][64];
  __shared__ float vsf[16][64];
  const int t = threadIdx.x;
  const int bh = blockIdx.x, chunk = blockIdx.y;   // (64, 16)
  const int b = bh >> 3, h = bh & 7;
  const int base_row = b * 8192 + chunk * 512;
  const int lane = t & 63, wave = t >> 6;
  const int dk0 = (lane & 7) * 8, dv0 = (lane >> 3) * 8;
  const int half = t >> 7, tt = t & 127;
  const int sr = tt >> 3, u = tt & 7;
  const int col = (half ? 1024 : 512) + h * 64 + u * 8;
  const unsigned short* src = qkv + (size_t)(base_row + sr) * 1536 + col;
  float* dstlds = half ? &vsf[sr][u * 8] : &ksf[sr][u * 8];
  float acc[8][8] = {};

  for (int it = 0; it < 32; ++it) {
    __syncthreads();
    union { int4 v; unsigned short s[8]; } raw;
    raw.v = *(const int4*)(src + (size_t)it * 16 * 1536);
    float4 lo = { bf2f(raw.s[0]), bf2f(raw.s[1]), bf2f(raw.s[2]), bf2f(raw.s[3]) };
    float4 hi = { bf2f(raw.s[4]), bf2f(raw.s[5]), bf2f(raw.s[6]), bf2f(raw.s[7]) };
    *(float4*)dstlds = lo;
    *(float4*)(dstlds + 4) = hi;
    __syncthreads();
    #pragma unroll
    for (int rr = 0; rr < 4; ++rr) {
      int r = rr * 4 + wave;
      float4 ka = *(const float4*)&ksf[r][dk0];
      float4 kb = *(const float4*)&ksf[r][dk0 + 4];
      float4 va = *(const float4*)&vsf[r][dv0];
      float4 vb = *(const float4*)&vsf[r][dv0 + 4];
      float kf[8] = { ka.x, ka.y, ka.z, ka.w, kb.x, kb.y, kb.z, kb.w };
      float vf[8] = { va.x, va.y, va.z, va.w, vb.x, vb.y, vb.z, vb.w };
      #pragma unroll
      for (int i = 0; i < 8; ++i)
        #pragma unroll
        for (int j = 0; j < 8; ++j)
          acc[i][j] = fmaf(kf[i], vf[j], acc[i][j]);
    }
  }
  float* dst = kvpart + ((size_t)(chunk * 4 + wave) * 64 + bh) * 4096;
  #pragma unroll
  for (int i = 0; i < 8; ++i) {
    *(float4*)&dst[(dk0 + i) * 64 + dv0]     = (float4){ acc[i][0], acc[i][1], acc[i][2], acc[i][3] };
    *(float4*)&dst[(dk0 + i) * 64 + dv0 + 4] = (float4){ acc[i][4], acc[i][5], acc[i][6], acc[i][7] };
  }
}

// ---------------------------------------------------------------------------
// reduce 64 slice partials -> kvbuf[bh][4096]. grid (64 bh, 8 seg) so all CUs
// participate (old 64-block version left 3/4 of the chip idle).
// ---------------------------------------------------------------------------
__global__ __launch_bounds__(256)
void kv_reduce_kernel(const float* __restrict__ kvpart, float* __restrict__ kvbuf)
{
  const int bh = blockIdx.x, seg = blockIdx.y, t = threadIdx.x;
  #pragma unroll
  for (int e = 0; e < 2; ++e) {
    int i = seg * 512 + e * 256 + t;
    float s = 0.f;
    for (int c = 0; c < 64; ++c) s += kvpart[((size_t)c * 64 + bh) * 4096 + i];
    kvbuf[(size_t)bh * 4096 + i] = s;
  }
}

// ---------------------------------------------------------------------------
// W2t[b][d][(h,k)] = sum_v (kv[b,h][k][v]*gamma[h]/||kv row||) * Wo[h*64+v][d]
// ---------------------------------------------------------------------------
__global__ __launch_bounds__(256)
void build_w2t_kernel(const float* __restrict__ kvbuf, const float* __restrict__ Wo,
                      const float* __restrict__ gamma, unsigned short* __restrict__ W2t)
{
  __shared__ float WoS[512][16];
  const int b = blockIdx.x, dt = blockIdx.y;
  const int d0 = dt * 16;
  const int t = threadIdx.x;
  for (int i = 0; i < 32; ++i) {
    int flat = i * 256 + t;
    int rr_ = flat >> 4, c = flat & 15;
    WoS[rr_][c] = Wo[(size_t)rr_ * 512 + d0 + c];
  }
  __syncthreads();
  for (int rr = 0; rr < 2; ++rr) {
    int r = rr * 256 + t;
    int h = r >> 6, k = r & 63;
    const float* krow = kvbuf + ((size_t)b * 8 + h) * 4096 + (size_t)k * 64;
    float ss = 0.f;
    #pragma unroll
    for (int v = 0; v < 64; v += 4) {
      float4 x = *(const float4*)&krow[v];
      ss += x.x * x.x + x.y * x.y + x.z * x.z + x.w * x.w;
    }
    float scale = gamma[h] * rsqrtf(ss);
    f4v accv[4];
    #pragma unroll
    for (int j = 0; j < 4; ++j) accv[j] = (f4v){0.f, 0.f, 0.f, 0.f};
    for (int v = 0; v < 64; ++v) {
      float m = krow[v] * scale;
      const float* w = &WoS[h * 64 + v][0];
      #pragma unroll
      for (int j4 = 0; j4 < 4; ++j4) {
        float4 ww = *(const float4*)&w[j4 * 4];
        accv[j4][0] = fmaf(m, ww.x, accv[j4][0]);
        accv[j4][1] = fmaf(m, ww.y, accv[j4][1]);
        accv[j4][2] = fmaf(m, ww.z, accv[j4][2]);
        accv[j4][3] = fmaf(m, ww.w, accv[j4][3]);
      }
    }
    #pragma unroll
    for (int j = 0; j < 16; ++j)
      W2t[((size_t)b * 512 + d0 + j) * 512 + r] = f2bf(accv[j >> 2][j & 3]);
  }
}

// ---------------------------------------------------------------------------
// GEMM3: Y[b] = qhat[b] @ W2t[b]^T + bo, fp32 out. Same 2-phase pipelined
// template as GEMM1. 1D 2048 grid; XCD swizzle maps each XCD chunk onto
// exactly one batch's W2t (512 KB) -> B L2-resident.
// ---------------------------------------------------------------------------
__global__ __launch_bounds__(256, 2)
void gemm_out_kernel(const unsigned short* __restrict__ qkv,
                     const unsigned short* __restrict__ W2t,
                     const float* __restrict__ bo,
                     float* __restrict__ out)
{
  __shared__ short As[2][8192];
  __shared__ short Bs[2][8192];
  const int t = threadIdx.x;
  const int o = blockIdx.x;                   // 2048 blocks
  const int swz = (o & 7) * 256 + (o >> 3);   // bijective XCD swizzle
  const int nb = swz & 3, rb = swz >> 2;      // nb fast; 64 rb per XCD = 1 batch
  const int wave = t >> 6, lane = t & 63;
  const int wm = wave & 1, wn = wave >> 1;
  const int quad = lane >> 4, l16 = lane & 15;
  const int row0 = rb * 128;
  const int ncol0 = nb * 128;
  const unsigned short* Wb = W2t + (size_t)(rb >> 6) * 262144;

  const unsigned short* ap[4];
  const unsigned short* bp[4];
  int ldst[4];
  #pragma unroll
  for (int i = 0; i < 4; ++i) {
    int s = i * 256 + t;
    int m = s >> 3;
    int kb = (s & 7) ^ (m & 7);
    ap[i] = qkv + (size_t)(row0 + m) * 1536 + kb * 8;
    bp[i] = Wb + (size_t)(ncol0 + m) * 512 + kb * 8;
    ldst[i] = s * 8;
  }

  f4v acc[4][4];
  #pragma unroll
  for (int i = 0; i < 4; ++i)
    #pragma unroll
    for (int j = 0; j < 4; ++j) acc[i][j] = (f4v){0.f, 0.f, 0.f, 0.f};

  #pragma unroll
  for (int i = 0; i < 4; ++i) {
    gld16(ap[i], &As[0][ldst[i]]);
    gld16(bp[i], &Bs[0][ldst[i]]);
  }
  TILE_SYNC();

  for (int kt = 0; kt < 8; ++kt) {
    const int cur = kt & 1;
    if (kt < 7) {
      const int koff = (kt + 1) * 64;
      #pragma unroll
      for (int i = 0; i < 4; ++i) {
        gld16(ap[i] + koff, &As[cur ^ 1][ldst[i]]);
        gld16(bp[i] + koff, &Bs[cur ^ 1][ldst[i]]);
      }
    }
    #pragma unroll
    for (int ks = 0; ks < 2; ++ks) {
      s8v a[4], b[4];
      #pragma unroll
      for (int mi = 0; mi < 4; ++mi) {
        int r = wm * 64 + mi * 16 + l16;
        int slot = r * 8 + ((ks * 4 + quad) ^ (r & 7));
        a[mi] = *(const s8v*)&As[cur][slot * 8];
      }
      #pragma unroll
      for (int nj = 0; nj < 4; ++nj) {
        int r = wn * 64 + nj * 16 + l16;
        int slot = r * 8 + ((ks * 4 + quad) ^ (r & 7));
        b[nj] = *(const s8v*)&Bs[cur][slot * 8];
      }
      #pragma unroll
      for (int mi = 0; mi < 4; ++mi)
        #pragma unroll
        for (int nj = 0; nj < 4; ++nj)
          acc[mi][nj] = __builtin_amdgcn_mfma_f32_16x16x32_bf16(a[mi], b[nj], acc[mi][nj], 0, 0, 0);
    }
    TILE_SYNC();
  }

  const int colbase = ncol0 + wn * 64;
  #pragma unroll
  for (int nj = 0; nj < 4; ++nj) {
    float bias = bo[colbase + nj * 16 + l16];
    #pragma unroll
    for (int mi = 0; mi < 4; ++mi)
      #pragma unroll
      for (int rr = 0; rr < 4; ++rr) {
        int row = row0 + wm * 64 + mi * 16 + quad * 4 + rr;
        int col = colbase + nj * 16 + l16;
        out[(size_t)row * 512 + col] = acc[mi][nj][rr] + bias;
      }
  }
}

// ---------------------------------------------------------------------------
extern "C" void kernel_launch(void* const* d_in, const int* in_sizes, int n_in,
                              void* d_out, int out_size, void* d_ws, size_t ws_size,
                              hipStream_t stream)
{
  (void)in_sizes; (void)n_in; (void)out_size; (void)ws_size;
  const float* X     = (const float*)d_in[0];
  const float* Wq    = (const float*)d_in[1];
  const float* bq    = (const float*)d_in[2];
  const float* Wk    = (const float*)d_in[3];
  const float* bk    = (const float*)d_in[4];
  const float* Wv    = (const float*)d_in[5];
  const float* bv    = (const float*)d_in[6];
  const float* Wo    = (const float*)d_in[7];
  const float* bo    = (const float*)d_in[8];
  const float* gamma = (const float*)d_in[9];

  char* ws = (char*)d_ws;
  unsigned short* qkv = (unsigned short*)ws;                         // 201326592 B
  unsigned short* Xbf = (unsigned short*)(ws + 201326592);           // 67108864 B
  float* kvpart = (float*)(ws + 201326592);                          // aliases Xbf (dead after gemm1): 64 MiB
  unsigned short* Wt  = (unsigned short*)(ws + 201326592 + 67108864);          // 1572864 B
  float* kvbuf        = (float*)(ws + 201326592 + 67108864 + 1572864);         // 1048576 B
  unsigned short* W2t = (unsigned short*)(ws + 201326592 + 67108864 + 1572864 + 1048576); // 4194304 B

  dim3 blk(256);
  convert_x_kernel<<<16384, blk, 0, stream>>>(X, Xbf);
  transpose_w_kernel<<<dim3(8, 24), blk, 0, stream>>>(Wq, Wk, Wv, Wt);
  gemm_qkv_kernel<<<6144, blk, 0, stream>>>(Xbf, Wt, bq, bk, bv, gamma, qkv);
  kv_accum_kernel<<<dim3(64, 16), blk, 0, stream>>>(qkv, kvpart);
  kv_reduce_kernel<<<dim3(64, 8), blk, 0, stream>>>(kvpart, kvbuf);
  build_w2t_kernel<<<dim3(8, 32), blk, 0, stream>>>(kvbuf, Wo, gamma, W2t);
  gemm_out_kernel<<<2048, blk, 0, stream>>>(qkv, W2t, bo, (float*)d_out);
}

// Round 4
// 530.634 us; speedup vs baseline: 1.0875x; 1.0400x over previous
//
#include <hip/hip_runtime.h>

typedef __attribute__((ext_vector_type(8))) short s8v;
typedef __attribute__((ext_vector_type(4))) short s4v;
typedef __attribute__((ext_vector_type(4))) float f4v;

__device__ __forceinline__ unsigned short f2bf(float f) {
  unsigned int u = __float_as_uint(f);
  u += 0x7FFFu + ((u >> 16) & 1u);   // RNE
  return (unsigned short)(u >> 16);
}
__device__ __forceinline__ float bf2f(unsigned short s) {
  return __uint_as_float(((unsigned int)s) << 16);
}

// async global->LDS 16B: lane i deposits at wave-uniform base + i*16
__device__ __forceinline__ void gld16(const void* g, void* l) {
  __builtin_amdgcn_global_load_lds(
      (const __attribute__((address_space(1))) unsigned int*)g,
      (__attribute__((address_space(3))) unsigned int*)l, 16, 0, 0);
}

// fused wait+barrier: memory-clobbered asm so no LDS op can be hoisted between
// the per-wave drain and the cross-wave barrier (tile-handoff point).
#define TILE_SYNC() asm volatile("s_waitcnt vmcnt(0) lgkmcnt(0)\n\ts_barrier" ::: "memory")

// ---------------------------------------------------------------------------
// Pass 0a: X fp32 [65536,512] -> Xbf bf16.
// ---------------------------------------------------------------------------
__global__ __launch_bounds__(256)
void convert_x_kernel(const float* __restrict__ X, unsigned short* __restrict__ Xbf)
{
  size_t base = ((size_t)blockIdx.x * 256 + threadIdx.x) * 8;
  float4 a = *(const float4*)&X[base];
  float4 b = *(const float4*)&X[base + 4];
  s8v p = (s8v){ (short)f2bf(a.x), (short)f2bf(a.y), (short)f2bf(a.z), (short)f2bf(a.w),
                 (short)f2bf(b.x), (short)f2bf(b.y), (short)f2bf(b.z), (short)f2bf(b.w) };
  *(s8v*)&Xbf[base] = p;
}

// ---------------------------------------------------------------------------
// Pass 0b: Wt[n][k] bf16, n = 0..511 Wq | 512..1023 Wk | 1024..1535 Wv.
// ---------------------------------------------------------------------------
__global__ __launch_bounds__(256)
void transpose_w_kernel(const float* __restrict__ Wq, const float* __restrict__ Wk,
                        const float* __restrict__ Wv, unsigned short* __restrict__ Wt)
{
  __shared__ float T[64][68];
  const int kt = blockIdx.x, nt = blockIdx.y;
  const float* W = (nt < 8) ? Wq : (nt < 16 ? Wk : Wv);
  const int n0 = (nt & 7) * 64, k0 = kt * 64;
  const int t = threadIdx.x;
  #pragma unroll
  for (int it = 0; it < 4; ++it) {
    int idx = it * 256 + t;
    int k = idx >> 4, n4 = (idx & 15) << 2;
    *(float4*)&T[k][n4] = *(const float4*)&W[(size_t)(k0 + k) * 512 + n0 + n4];
  }
  __syncthreads();
  #pragma unroll
  for (int it = 0; it < 2; ++it) {
    int idx = it * 256 + t;
    int n = idx >> 3, k8 = (idx & 7) << 3;
    s8v p;
    #pragma unroll
    for (int j = 0; j < 8; ++j) p[j] = (short)f2bf(T[k8 + j][n]);
    *(s8v*)&Wt[((size_t)nt * 64 + n) * 512 + k0 + k8] = p;
  }
}

// ---------------------------------------------------------------------------
// GEMM1: qkv = Xbf @ Wt^T (+bias), q-part normalized per head * gamma.
// 256x256 tile, 8 waves (2M x 4N), K-tiles of 64, double-buffered LDS,
// 4-phase pipeline per K-tile:
//   phase0: prefetch grp0 (t+1) | load B-frags + A-frags(qm0) | MFMA (qm0,qn01)
//   phase1: prefetch grp1 (t+1) |                             | MFMA (qm0,qn23)
//   phase2:                     | load A-frags(qm1)           | MFMA (qm1,qn01)
//   phase3:                     | MFMA (qm1,qn23) | vmcnt+lgkm drain + barrier
// One vmcnt(0) drain per tile, issued ~3 phases (~500cy MFMA) after the
// prefetch -> latency hidden (round-3's 2-phase exposed it: MfmaUtil 26%).
// Mid-phase raw s_barriers carry no vmcnt drain. setprio(1) around MFMA
// clusters (T5: pays only with phase role-split). Granule XOR swizzle keeps
// ds_read_b128 2-way (free). XCD swizzle: 192 contiguous swz per XCD, nb
// fast -> A read once per XCD (round 3 verified: FETCH 266->45 MB).
// ---------------------------------------------------------------------------
__global__ __launch_bounds__(512, 2)
void gemm_qkv_kernel(const unsigned short* __restrict__ Xbf,
                     const unsigned short* __restrict__ Wt,
                     const float* __restrict__ bq, const float* __restrict__ bk,
                     const float* __restrict__ bv,
                     const float* __restrict__ gamma,
                     unsigned short* __restrict__ qkv)
{
  __shared__ short As[2][16384];   // 2 x 32 KB (256 rows x 64 cols bf16)
  __shared__ short Bs[2][16384];
  const int t = threadIdx.x;
  const int o = blockIdx.x;                    // 1536 blocks
  const int swz = (o & 7) * 192 + (o >> 3);    // bijective XCD swizzle
  const int nb = swz % 6, rb = swz / 6;        // nb fast within XCD chunk
  const int wave = t >> 6, lane = t & 63;
  const int wm = wave & 1, wn = wave >> 1;
  const int quad = lane >> 4, l16 = lane & 15;
  const int row0 = rb * 256, ncol0 = nb * 256;

  const unsigned short* ap[4];
  const unsigned short* bp[4];
  int ldst[4];
  #pragma unroll
  for (int i = 0; i < 4; ++i) {
    int s = i * 512 + t;
    int m = s >> 3, kb = (s & 7) ^ (m & 7);
    ap[i] = Xbf + (size_t)(row0 + m) * 512 + kb * 8;
    bp[i] = Wt + (size_t)(ncol0 + m) * 512 + kb * 8;
    ldst[i] = s * 8;
  }

  f4v acc[8][4];
  #pragma unroll
  for (int i = 0; i < 8; ++i)
    #pragma unroll
    for (int j = 0; j < 4; ++j) acc[i][j] = (f4v){0.f, 0.f, 0.f, 0.f};

  // prologue: stage tile 0
  #pragma unroll
  for (int i = 0; i < 4; ++i) {
    gld16(ap[i], &As[0][ldst[i]]);
    gld16(bp[i], &Bs[0][ldst[i]]);
  }
  TILE_SYNC();

  for (int kt = 0; kt < 8; ++kt) {
    const int cur = kt & 1;
    const short* Ac = As[cur];
    const short* Bc = Bs[cur];
    short* An = (short*)As[cur ^ 1];
    short* Bn = (short*)Bs[cur ^ 1];
    const int koff = (kt + 1) * 64;
    const bool pf = kt < 7;
    s8v afr[4][2], bfr[4][2];

    // ---------------- phase 0: quadrant (qm0, qn01) ----------------
    if (pf) {
      gld16(ap[0] + koff, &An[ldst[0]]);
      gld16(ap[1] + koff, &An[ldst[1]]);
      gld16(bp[0] + koff, &Bn[ldst[0]]);
      gld16(bp[1] + koff, &Bn[ldst[1]]);
    }
    #pragma unroll
    for (int nj = 0; nj < 4; ++nj)
      #pragma unroll
      for (int ks = 0; ks < 2; ++ks) {
        int r = wn * 64 + nj * 16 + l16;
        bfr[nj][ks] = *(const s8v*)&Bc[(r * 8 + ((ks * 4 + quad) ^ (r & 7))) * 8];
      }
    #pragma unroll
    for (int mi = 0; mi < 4; ++mi)
      #pragma unroll
      for (int ks = 0; ks < 2; ++ks) {
        int r = wm * 128 + mi * 16 + l16;
        afr[mi][ks] = *(const s8v*)&Ac[(r * 8 + ((ks * 4 + quad) ^ (r & 7))) * 8];
      }
    __builtin_amdgcn_s_setprio(1);
    #pragma unroll
    for (int mi = 0; mi < 4; ++mi)
      #pragma unroll
      for (int nj = 0; nj < 2; ++nj)
        #pragma unroll
        for (int ks = 0; ks < 2; ++ks)
          acc[mi][nj] = __builtin_amdgcn_mfma_f32_16x16x32_bf16(afr[mi][ks], bfr[nj][ks], acc[mi][nj], 0, 0, 0);
    __builtin_amdgcn_s_setprio(0);
    __builtin_amdgcn_s_barrier();

    // ---------------- phase 1: quadrant (qm0, qn23) ----------------
    if (pf) {
      gld16(ap[2] + koff, &An[ldst[2]]);
      gld16(ap[3] + koff, &An[ldst[3]]);
      gld16(bp[2] + koff, &Bn[ldst[2]]);
      gld16(bp[3] + koff, &Bn[ldst[3]]);
    }
    __builtin_amdgcn_s_setprio(1);
    #pragma unroll
    for (int mi = 0; mi < 4; ++mi)
      #pragma unroll
      for (int nj = 2; nj < 4; ++nj)
        #pragma unroll
        for (int ks = 0; ks < 2; ++ks)
          acc[mi][nj] = __builtin_amdgcn_mfma_f32_16x16x32_bf16(afr[mi][ks], bfr[nj][ks], acc[mi][nj], 0, 0, 0);
    __builtin_amdgcn_s_setprio(0);
    __builtin_amdgcn_s_barrier();

    // ---------------- phase 2: quadrant (qm1, qn01) ----------------
    #pragma unroll
    for (int mi = 0; mi < 4; ++mi)
      #pragma unroll
      for (int ks = 0; ks < 2; ++ks) {
        int r = wm * 128 + (4 + mi) * 16 + l16;
        afr[mi][ks] = *(const s8v*)&Ac[(r * 8 + ((ks * 4 + quad) ^ (r & 7))) * 8];
      }
    __builtin_amdgcn_s_setprio(1);
    #pragma unroll
    for (int mi = 0; mi < 4; ++mi)
      #pragma unroll
      for (int nj = 0; nj < 2; ++nj)
        #pragma unroll
        for (int ks = 0; ks < 2; ++ks)
          acc[4 + mi][nj] = __builtin_amdgcn_mfma_f32_16x16x32_bf16(afr[mi][ks], bfr[nj][ks], acc[4 + mi][nj], 0, 0, 0);
    __builtin_amdgcn_s_setprio(0);
    __builtin_amdgcn_s_barrier();

    // ---------------- phase 3: quadrant (qm1, qn23) + tile handoff ----------------
    __builtin_amdgcn_s_setprio(1);
    #pragma unroll
    for (int mi = 0; mi < 4; ++mi)
      #pragma unroll
      for (int nj = 2; nj < 4; ++nj)
        #pragma unroll
        for (int ks = 0; ks < 2; ++ks)
          acc[4 + mi][nj] = __builtin_amdgcn_mfma_f32_16x16x32_bf16(afr[mi][ks], bfr[nj][ks], acc[4 + mi][nj], 0, 0, 0);
    __builtin_amdgcn_s_setprio(0);
    TILE_SYNC();
  }

  // bias (zeros here, kept for semantics)
  #pragma unroll
  for (int nj = 0; nj < 4; ++nj) {
    int colg = ncol0 + wn * 64 + nj * 16 + l16;
    float bias;
    if (colg < 512) bias = bq[colg];
    else if (colg < 1024) bias = bk[colg - 512];
    else bias = bv[colg - 1024];
    #pragma unroll
    for (int mi = 0; mi < 8; ++mi) {
      acc[mi][nj][0] += bias; acc[mi][nj][1] += bias;
      acc[mi][nj][2] += bias; acc[mi][nj][3] += bias;
    }
  }

  // fused q-normalization: wave's 64 cols == one head; norm over DK=64 per row
  if (nb < 2) {
    float g = gamma[nb * 4 + wn];
    #pragma unroll
    for (int mi = 0; mi < 8; ++mi)
      #pragma unroll
      for (int rr = 0; rr < 4; ++rr) {
        float ss = acc[mi][0][rr] * acc[mi][0][rr] + acc[mi][1][rr] * acc[mi][1][rr]
                 + acc[mi][2][rr] * acc[mi][2][rr] + acc[mi][3][rr] * acc[mi][3][rr];
        ss += __shfl_xor(ss, 1);
        ss += __shfl_xor(ss, 2);
        ss += __shfl_xor(ss, 4);
        ss += __shfl_xor(ss, 8);
        float scale = g * rsqrtf(ss);
        acc[mi][0][rr] *= scale; acc[mi][1][rr] *= scale;
        acc[mi][2][rr] *= scale; acc[mi][3][rr] *= scale;
      }
  }

  const int colbase = ncol0 + wn * 64;
  #pragma unroll
  for (int mi = 0; mi < 8; ++mi)
    #pragma unroll
    for (int nj = 0; nj < 4; ++nj)
      #pragma unroll
      for (int rr = 0; rr < 4; ++rr) {
        int row = row0 + wm * 128 + mi * 16 + quad * 4 + rr;
        int col = colbase + nj * 16 + l16;
        qkv[(size_t)row * 1536 + col] = f2bf(acc[mi][nj][rr]);
      }
}

// ---------------------------------------------------------------------------
// kv partials: per (bh, chunk of 512 rows). 8x8 per lane, waves split rows.
// 64 partial slices (chunk*4+wave), no atomics.
// ---------------------------------------------------------------------------
__global__ __launch_bounds__(256)
void kv_accum_kernel(const unsigned short* __restrict__ qkv, float* __restrict__ kvpart)
{
  __shared__ float ksf[16][64];
  __shared__ float vsf[16][64];
  const int t = threadIdx.x;
  const int bh = blockIdx.x, chunk = blockIdx.y;   // (64, 16)
  const int b = bh >> 3, h = bh & 7;
  const int base_row = b * 8192 + chunk * 512;
  const int lane = t & 63, wave = t >> 6;
  const int dk0 = (lane & 7) * 8, dv0 = (lane >> 3) * 8;
  const int half = t >> 7, tt = t & 127;
  const int sr = tt >> 3, u = tt & 7;
  const int col = (half ? 1024 : 512) + h * 64 + u * 8;
  const unsigned short* src = qkv + (size_t)(base_row + sr) * 1536 + col;
  float* dstlds = half ? &vsf[sr][u * 8] : &ksf[sr][u * 8];
  float acc[8][8] = {};

  for (int it = 0; it < 32; ++it) {
    __syncthreads();
    union { int4 v; unsigned short s[8]; } raw;
    raw.v = *(const int4*)(src + (size_t)it * 16 * 1536);
    float4 lo = { bf2f(raw.s[0]), bf2f(raw.s[1]), bf2f(raw.s[2]), bf2f(raw.s[3]) };
    float4 hi = { bf2f(raw.s[4]), bf2f(raw.s[5]), bf2f(raw.s[6]), bf2f(raw.s[7]) };
    *(float4*)dstlds = lo;
    *(float4*)(dstlds + 4) = hi;
    __syncthreads();
    #pragma unroll
    for (int rr = 0; rr < 4; ++rr) {
      int r = rr * 4 + wave;
      float4 ka = *(const float4*)&ksf[r][dk0];
      float4 kb = *(const float4*)&ksf[r][dk0 + 4];
      float4 va = *(const float4*)&vsf[r][dv0];
      float4 vb = *(const float4*)&vsf[r][dv0 + 4];
      float kf[8] = { ka.x, ka.y, ka.z, ka.w, kb.x, kb.y, kb.z, kb.w };
      float vf[8] = { va.x, va.y, va.z, va.w, vb.x, vb.y, vb.z, vb.w };
      #pragma unroll
      for (int i = 0; i < 8; ++i)
        #pragma unroll
        for (int j = 0; j < 8; ++j)
          acc[i][j] = fmaf(kf[i], vf[j], acc[i][j]);
    }
  }
  float* dst = kvpart + ((size_t)(chunk * 4 + wave) * 64 + bh) * 4096;
  #pragma unroll
  for (int i = 0; i < 8; ++i) {
    *(float4*)&dst[(dk0 + i) * 64 + dv0]     = (float4){ acc[i][0], acc[i][1], acc[i][2], acc[i][3] };
    *(float4*)&dst[(dk0 + i) * 64 + dv0 + 4] = (float4){ acc[i][4], acc[i][5], acc[i][6], acc[i][7] };
  }
}

// ---------------------------------------------------------------------------
// reduce 64 slice partials -> kvbuf[bh][4096]. grid (64 bh, 8 seg) so all CUs
// participate.
// ---------------------------------------------------------------------------
__global__ __launch_bounds__(256)
void kv_reduce_kernel(const float* __restrict__ kvpart, float* __restrict__ kvbuf)
{
  const int bh = blockIdx.x, seg = blockIdx.y, t = threadIdx.x;
  #pragma unroll
  for (int e = 0; e < 2; ++e) {
    int i = seg * 512 + e * 256 + t;
    float s = 0.f;
    for (int c = 0; c < 64; ++c) s += kvpart[((size_t)c * 64 + bh) * 4096 + i];
    kvbuf[(size_t)bh * 4096 + i] = s;
  }
}

// ---------------------------------------------------------------------------
// W2t[b][d][(h,k)] = sum_v (kv[b,h][k][v]*gamma[h]/||kv row||) * Wo[h*64+v][d]
// ---------------------------------------------------------------------------
__global__ __launch_bounds__(256)
void build_w2t_kernel(const float* __restrict__ kvbuf, const float* __restrict__ Wo,
                      const float* __restrict__ gamma, unsigned short* __restrict__ W2t)
{
  __shared__ float WoS[512][16];
  const int b = blockIdx.x, dt = blockIdx.y;
  const int d0 = dt * 16;
  const int t = threadIdx.x;
  for (int i = 0; i < 32; ++i) {
    int flat = i * 256 + t;
    int rr_ = flat >> 4, c = flat & 15;
    WoS[rr_][c] = Wo[(size_t)rr_ * 512 + d0 + c];
  }
  __syncthreads();
  for (int rr = 0; rr < 2; ++rr) {
    int r = rr * 256 + t;
    int h = r >> 6, k = r & 63;
    const float* krow = kvbuf + ((size_t)b * 8 + h) * 4096 + (size_t)k * 64;
    float ss = 0.f;
    #pragma unroll
    for (int v = 0; v < 64; v += 4) {
      float4 x = *(const float4*)&krow[v];
      ss += x.x * x.x + x.y * x.y + x.z * x.z + x.w * x.w;
    }
    float scale = gamma[h] * rsqrtf(ss);
    f4v accv[4];
    #pragma unroll
    for (int j = 0; j < 4; ++j) accv[j] = (f4v){0.f, 0.f, 0.f, 0.f};
    for (int v = 0; v < 64; ++v) {
      float m = krow[v] * scale;
      const float* w = &WoS[h * 64 + v][0];
      #pragma unroll
      for (int j4 = 0; j4 < 4; ++j4) {
        float4 ww = *(const float4*)&w[j4 * 4];
        accv[j4][0] = fmaf(m, ww.x, accv[j4][0]);
        accv[j4][1] = fmaf(m, ww.y, accv[j4][1]);
        accv[j4][2] = fmaf(m, ww.z, accv[j4][2]);
        accv[j4][3] = fmaf(m, ww.w, accv[j4][3]);
      }
    }
    #pragma unroll
    for (int j = 0; j < 16; ++j)
      W2t[((size_t)b * 512 + d0 + j) * 512 + r] = f2bf(accv[j >> 2][j & 3]);
  }
}

// ---------------------------------------------------------------------------
// GEMM3: Y[b] = qhat[b] @ W2t[b]^T + bo, fp32 out. Same 256x256 4-phase
// pipelined template as GEMM1. 512 blocks; XCD swizzle maps exactly one
// batch's W2t (512 KB) per XCD -> B L2-resident.
// ---------------------------------------------------------------------------
__global__ __launch_bounds__(512, 2)
void gemm_out_kernel(const unsigned short* __restrict__ qkv,
                     const unsigned short* __restrict__ W2t,
                     const float* __restrict__ bo,
                     float* __restrict__ out)
{
  __shared__ short As[2][16384];
  __shared__ short Bs[2][16384];
  const int t = threadIdx.x;
  const int o = blockIdx.x;                  // 512 blocks
  const int swz = (o & 7) * 64 + (o >> 3);   // bijective XCD swizzle
  const int nb = swz & 1, rb = swz >> 1;     // nb fast; 32 rb per XCD = 1 batch
  const int wave = t >> 6, lane = t & 63;
  const int wm = wave & 1, wn = wave >> 1;
  const int quad = lane >> 4, l16 = lane & 15;
  const int row0 = rb * 256, ncol0 = nb * 256;
  const unsigned short* Wb = W2t + (size_t)(rb >> 5) * 262144;

  const unsigned short* ap[4];
  const unsigned short* bp[4];
  int ldst[4];
  #pragma unroll
  for (int i = 0; i < 4; ++i) {
    int s = i * 512 + t;
    int m = s >> 3, kb = (s & 7) ^ (m & 7);
    ap[i] = qkv + (size_t)(row0 + m) * 1536 + kb * 8;
    bp[i] = Wb + (size_t)(ncol0 + m) * 512 + kb * 8;
    ldst[i] = s * 8;
  }

  f4v acc[8][4];
  #pragma unroll
  for (int i = 0; i < 8; ++i)
    #pragma unroll
    for (int j = 0; j < 4; ++j) acc[i][j] = (f4v){0.f, 0.f, 0.f, 0.f};

  #pragma unroll
  for (int i = 0; i < 4; ++i) {
    gld16(ap[i], &As[0][ldst[i]]);
    gld16(bp[i], &Bs[0][ldst[i]]);
  }
  TILE_SYNC();

  for (int kt = 0; kt < 8; ++kt) {
    const int cur = kt & 1;
    const short* Ac = As[cur];
    const short* Bc = Bs[cur];
    short* An = (short*)As[cur ^ 1];
    short* Bn = (short*)Bs[cur ^ 1];
    const int koff = (kt + 1) * 64;
    const bool pf = kt < 7;
    s8v afr[4][2], bfr[4][2];

    // phase 0
    if (pf) {
      gld16(ap[0] + koff, &An[ldst[0]]);
      gld16(ap[1] + koff, &An[ldst[1]]);
      gld16(bp[0] + koff, &Bn[ldst[0]]);
      gld16(bp[1] + koff, &Bn[ldst[1]]);
    }
    #pragma unroll
    for (int nj = 0; nj < 4; ++nj)
      #pragma unroll
      for (int ks = 0; ks < 2; ++ks) {
        int r = wn * 64 + nj * 16 + l16;
        bfr[nj][ks] = *(const s8v*)&Bc[(r * 8 + ((ks * 4 + quad) ^ (r & 7))) * 8];
      }
    #pragma unroll
    for (int mi = 0; mi < 4; ++mi)
      #pragma unroll
      for (int ks = 0; ks < 2; ++ks) {
        int r = wm * 128 + mi * 16 + l16;
        afr[mi][ks] = *(const s8v*)&Ac[(r * 8 + ((ks * 4 + quad) ^ (r & 7))) * 8];
      }
    __builtin_amdgcn_s_setprio(1);
    #pragma unroll
    for (int mi = 0; mi < 4; ++mi)
      #pragma unroll
      for (int nj = 0; nj < 2; ++nj)
        #pragma unroll
        for (int ks = 0; ks < 2; ++ks)
          acc[mi][nj] = __builtin_amdgcn_mfma_f32_16x16x32_bf16(afr[mi][ks], bfr[nj][ks], acc[mi][nj], 0, 0, 0);
    __builtin_amdgcn_s_setprio(0);
    __builtin_amdgcn_s_barrier();

    // phase 1
    if (pf) {
      gld16(ap[2] + koff, &An[ldst[2]]);
      gld16(ap[3] + koff, &An[ldst[3]]);
      gld16(bp[2] + koff, &Bn[ldst[2]]);
      gld16(bp[3] + koff, &Bn[ldst[3]]);
    }
    __builtin_amdgcn_s_setprio(1);
    #pragma unroll
    for (int mi = 0; mi < 4; ++mi)
      #pragma unroll
      for (int nj = 2; nj < 4; ++nj)
        #pragma unroll
        for (int ks = 0; ks < 2; ++ks)
          acc[mi][nj] = __builtin_amdgcn_mfma_f32_16x16x32_bf16(afr[mi][ks], bfr[nj][ks], acc[mi][nj], 0, 0, 0);
    __builtin_amdgcn_s_setprio(0);
    __builtin_amdgcn_s_barrier();

    // phase 2
    #pragma unroll
    for (int mi = 0; mi < 4; ++mi)
      #pragma unroll
      for (int ks = 0; ks < 2; ++ks) {
        int r = wm * 128 + (4 + mi) * 16 + l16;
        afr[mi][ks] = *(const s8v*)&Ac[(r * 8 + ((ks * 4 + quad) ^ (r & 7))) * 8];
      }
    __builtin_amdgcn_s_setprio(1);
    #pragma unroll
    for (int mi = 0; mi < 4; ++mi)
      #pragma unroll
      for (int nj = 0; nj < 2; ++nj)
        #pragma unroll
        for (int ks = 0; ks < 2; ++ks)
          acc[4 + mi][nj] = __builtin_amdgcn_mfma_f32_16x16x32_bf16(afr[mi][ks], bfr[nj][ks], acc[4 + mi][nj], 0, 0, 0);
    __builtin_amdgcn_s_setprio(0);
    __builtin_amdgcn_s_barrier();

    // phase 3
    __builtin_amdgcn_s_setprio(1);
    #pragma unroll
    for (int mi = 0; mi < 4; ++mi)
      #pragma unroll
      for (int nj = 2; nj < 4; ++nj)
        #pragma unroll
        for (int ks = 0; ks < 2; ++ks)
          acc[4 + mi][nj] = __builtin_amdgcn_mfma_f32_16x16x32_bf16(afr[mi][ks], bfr[nj][ks], acc[4 + mi][nj], 0, 0, 0);
    __builtin_amdgcn_s_setprio(0);
    TILE_SYNC();
  }

  const int colbase = ncol0 + wn * 64;
  #pragma unroll
  for (int nj = 0; nj < 4; ++nj) {
    float bias = bo[colbase + nj * 16 + l16];
    #pragma unroll
    for (int mi = 0; mi < 8; ++mi)
      #pragma unroll
      for (int rr = 0; rr < 4; ++rr) {
        int row = row0 + wm * 128 + mi * 16 + quad * 4 + rr;
        int col = colbase + nj * 16 + l16;
        out[(size_t)row * 512 + col] = acc[mi][nj][rr] + bias;
      }
  }
}

// ---------------------------------------------------------------------------
extern "C" void kernel_launch(void* const* d_in, const int* in_sizes, int n_in,
                              void* d_out, int out_size, void* d_ws, size_t ws_size,
                              hipStream_t stream)
{
  (void)in_sizes; (void)n_in; (void)out_size; (void)ws_size;
  const float* X     = (const float*)d_in[0];
  const float* Wq    = (const float*)d_in[1];
  const float* bq    = (const float*)d_in[2];
  const float* Wk    = (const float*)d_in[3];
  const float* bk    = (const float*)d_in[4];
  const float* Wv    = (const float*)d_in[5];
  const float* bv    = (const float*)d_in[6];
  const float* Wo    = (const float*)d_in[7];
  const float* bo    = (const float*)d_in[8];
  const float* gamma = (const float*)d_in[9];

  char* ws = (char*)d_ws;
  unsigned short* qkv = (unsigned short*)ws;                         // 201326592 B
  unsigned short* Xbf = (unsigned short*)(ws + 201326592);           // 67108864 B
  float* kvpart = (float*)(ws + 201326592);                          // aliases Xbf (dead after gemm1): 64 MiB
  unsigned short* Wt  = (unsigned short*)(ws + 201326592 + 67108864);          // 1572864 B
  float* kvbuf        = (float*)(ws + 201326592 + 67108864 + 1572864);         // 1048576 B
  unsigned short* W2t = (unsigned short*)(ws + 201326592 + 67108864 + 1572864 + 1048576); // 4194304 B

  dim3 blk(256);
  convert_x_kernel<<<16384, blk, 0, stream>>>(X, Xbf);
  transpose_w_kernel<<<dim3(8, 24), blk, 0, stream>>>(Wq, Wk, Wv, Wt);
  gemm_qkv_kernel<<<1536, dim3(512), 0, stream>>>(Xbf, Wt, bq, bk, bv, gamma, qkv);
  kv_accum_kernel<<<dim3(64, 16), blk, 0, stream>>>(qkv, kvpart);
  kv_reduce_kernel<<<dim3(64, 8), blk, 0, stream>>>(kvpart, kvbuf);
  build_w2t_kernel<<<dim3(8, 32), blk, 0, stream>>>(kvbuf, Wo, gamma, W2t);
  gemm_out_kernel<<<512, dim3(512), 0, stream>>>(qkv, W2t, bo, (float*)d_out);
}

// Round 5
// 504.848 us; speedup vs baseline: 1.1431x; 1.0511x over previous
//
#include <hip/hip_runtime.h>

typedef __attribute__((ext_vector_type(8))) short s8v;
typedef __attribute__((ext_vector_type(4))) float f4v;

__device__ __forceinline__ unsigned short f2bf(float f) {
  unsigned int u = __float_as_uint(f);
  u += 0x7FFFu + ((u >> 16) & 1u);   // RNE
  return (unsigned short)(u >> 16);
}
__device__ __forceinline__ float bf2f(unsigned short s) {
  return __uint_as_float(((unsigned int)s) << 16);
}

// async global->LDS 16B: lane i deposits at wave-uniform base + i*16
__device__ __forceinline__ void gld16(const void* g, void* l) {
  __builtin_amdgcn_global_load_lds(
      (const __attribute__((address_space(1))) unsigned int*)g,
      (__attribute__((address_space(3))) unsigned int*)l, 16, 0, 0);
}

// fused wait+barrier (gemm_out template)
#define TILE_SYNC() asm volatile("s_waitcnt vmcnt(0) lgkmcnt(0)\n\ts_barrier" ::: "memory")

// ---------------------------------------------------------------------------
// Pass 0a: X fp32 [65536,512] -> Xbf bf16.
// ---------------------------------------------------------------------------
__global__ __launch_bounds__(256)
void convert_x_kernel(const float* __restrict__ X, unsigned short* __restrict__ Xbf)
{
  size_t base = ((size_t)blockIdx.x * 256 + threadIdx.x) * 8;
  float4 a = *(const float4*)&X[base];
  float4 b = *(const float4*)&X[base + 4];
  s8v p = (s8v){ (short)f2bf(a.x), (short)f2bf(a.y), (short)f2bf(a.z), (short)f2bf(a.w),
                 (short)f2bf(b.x), (short)f2bf(b.y), (short)f2bf(b.z), (short)f2bf(b.w) };
  *(s8v*)&Xbf[base] = p;
}

// ---------------------------------------------------------------------------
// Pass 0b: Wt[n][k] bf16, n = 0..511 Wq | 512..1023 Wk | 1024..1535 Wv.
// ---------------------------------------------------------------------------
__global__ __launch_bounds__(256)
void transpose_w_kernel(const float* __restrict__ Wq, const float* __restrict__ Wk,
                        const float* __restrict__ Wv, unsigned short* __restrict__ Wt)
{
  __shared__ float T[64][68];
  const int kt = blockIdx.x, nt = blockIdx.y;
  const float* W = (nt < 8) ? Wq : (nt < 16 ? Wk : Wv);
  const int n0 = (nt & 7) * 64, k0 = kt * 64;
  const int t = threadIdx.x;
  #pragma unroll
  for (int it = 0; it < 4; ++it) {
    int idx = it * 256 + t;
    int k = idx >> 4, n4 = (idx & 15) << 2;
    *(float4*)&T[k][n4] = *(const float4*)&W[(size_t)(k0 + k) * 512 + n0 + n4];
  }
  __syncthreads();
  #pragma unroll
  for (int it = 0; it < 2; ++it) {
    int idx = it * 256 + t;
    int n = idx >> 3, k8 = (idx & 7) << 3;
    s8v p;
    #pragma unroll
    for (int j = 0; j < 8; ++j) p[j] = (short)f2bf(T[k8 + j][n]);
    *(s8v*)&Wt[((size_t)nt * 64 + n) * 512 + k0 + k8] = p;
  }
}

// ---------------------------------------------------------------------------
// GEMM1 (round-0 structure, measured best 137us: 128x128 tile, 256 thr,
// single-buffer stage->sync->compute, 2+ independent blocks/CU do the latency
// hiding; rounds 3/4 proved pipelined variants regress this shape).
// Epilogue: q (nb<4) -> normalized qhat [65536][512];
//           k/v (nb>=4) -> TRANSPOSED kvT[sect][bh][dk=64][n=8192] bf16 so
//           kv_accum can be a coalesced direct-global MFMA kernel.
// ---------------------------------------------------------------------------
__global__ __launch_bounds__(256, 2)
void gemm_qkv_kernel(const unsigned short* __restrict__ Xbf,
                     const unsigned short* __restrict__ Wt,
                     const float* __restrict__ bq, const float* __restrict__ bk,
                     const float* __restrict__ bv,
                     const float* __restrict__ gamma,
                     unsigned short* __restrict__ qhat,
                     unsigned short* __restrict__ kvT)
{
  __shared__ short As[8192];   // 1024 granules x 16B = 16 KB
  __shared__ short Bs[8192];
  const int t = threadIdx.x;
  const int nb = blockIdx.x, rb = blockIdx.y;
  const int wave = t >> 6, lane = t & 63;
  const int wm = wave & 1, wn = wave >> 1;
  const int quad = lane >> 4, l16 = lane & 15;
  const int row0 = rb * 128;
  const int ncol0 = nb * 128;

  const unsigned short* ap[4];
  const unsigned short* bp[4];
  #pragma unroll
  for (int i = 0; i < 4; ++i) {
    int s = i * 256 + t;
    int m = s >> 3;
    int kb = (s & 7) ^ (m & 7);
    ap[i] = Xbf + (size_t)(row0 + m) * 512 + kb * 8;
    bp[i] = Wt + (size_t)(ncol0 + m) * 512 + kb * 8;
  }

  f4v acc[4][4];
  #pragma unroll
  for (int i = 0; i < 4; ++i)
    #pragma unroll
    for (int j = 0; j < 4; ++j) acc[i][j] = (f4v){0.f, 0.f, 0.f, 0.f};

  for (int kt = 0; kt < 512; kt += 64) {
    __syncthreads();
    #pragma unroll
    for (int i = 0; i < 4; ++i) {
      int s8 = (i * 256 + t) * 8;
      gld16(ap[i] + kt, &As[s8]);
      gld16(bp[i] + kt, &Bs[s8]);
    }
    __syncthreads();
    #pragma unroll
    for (int ks = 0; ks < 2; ++ks) {
      s8v a[4], b[4];
      #pragma unroll
      for (int mi = 0; mi < 4; ++mi) {
        int r = wm * 64 + mi * 16 + l16;
        int slot = r * 8 + ((ks * 4 + quad) ^ (r & 7));
        a[mi] = *(const s8v*)&As[slot * 8];
      }
      #pragma unroll
      for (int nj = 0; nj < 4; ++nj) {
        int r = wn * 64 + nj * 16 + l16;
        int slot = r * 8 + ((ks * 4 + quad) ^ (r & 7));
        b[nj] = *(const s8v*)&Bs[slot * 8];
      }
      #pragma unroll
      for (int mi = 0; mi < 4; ++mi)
        #pragma unroll
        for (int nj = 0; nj < 4; ++nj)
          acc[mi][nj] = __builtin_amdgcn_mfma_f32_16x16x32_bf16(a[mi], b[nj], acc[mi][nj], 0, 0, 0);
    }
  }

  if (nb < 4) {
    // q path: bias + per-head normalize * gamma, store qhat (pitch 512)
    #pragma unroll
    for (int nj = 0; nj < 4; ++nj) {
      int colg = ncol0 + wn * 64 + nj * 16 + l16;
      float bias = bq[colg];
      #pragma unroll
      for (int mi = 0; mi < 4; ++mi) {
        acc[mi][nj][0] += bias; acc[mi][nj][1] += bias;
        acc[mi][nj][2] += bias; acc[mi][nj][3] += bias;
      }
    }
    float g = gamma[nb * 2 + wn];
    #pragma unroll
    for (int mi = 0; mi < 4; ++mi)
      #pragma unroll
      for (int rr = 0; rr < 4; ++rr) {
        float ss = acc[mi][0][rr] * acc[mi][0][rr] + acc[mi][1][rr] * acc[mi][1][rr]
                 + acc[mi][2][rr] * acc[mi][2][rr] + acc[mi][3][rr] * acc[mi][3][rr];
        ss += __shfl_xor(ss, 1);
        ss += __shfl_xor(ss, 2);
        ss += __shfl_xor(ss, 4);
        ss += __shfl_xor(ss, 8);
        float scale = g * rsqrtf(ss);
        acc[mi][0][rr] *= scale; acc[mi][1][rr] *= scale;
        acc[mi][2][rr] *= scale; acc[mi][3][rr] *= scale;
      }
    const int colbase = ncol0 + wn * 64;
    #pragma unroll
    for (int mi = 0; mi < 4; ++mi)
      #pragma unroll
      for (int nj = 0; nj < 4; ++nj)
        #pragma unroll
        for (int rr = 0; rr < 4; ++rr) {
          int row = row0 + wm * 64 + mi * 16 + quad * 4 + rr;
          int col = colbase + nj * 16 + l16;
          qhat[(size_t)row * 512 + col] = f2bf(acc[mi][nj][rr]);
        }
  } else {
    // k/v path: bias + transposed store. Lane holds 4 consecutive n (rr) at
    // fixed (h, dk) -> pack 4 bf16 into 8B store, quads make 32B contiguous.
    const int sect = (nb - 4) >> 2;                  // 0=k, 1=v
    const float* bb = sect ? bv : bk;
    const int bidx = row0 >> 13;
    const int nb4 = (nb - 4) & 3;
    const int nrow = (row0 & 8191) + wm * 64 + quad * 4;
    #pragma unroll
    for (int nj = 0; nj < 4; ++nj) {
      int cis = nb4 * 128 + wn * 64 + nj * 16 + l16;  // col in section [0,512)
      float bias = bb[cis];
      int h = cis >> 6, dk = cis & 63;
      unsigned short* rowp = kvT + (size_t)((sect * 64 + bidx * 8 + h) * 64 + dk) * 8192;
      #pragma unroll
      for (int mi = 0; mi < 4; ++mi) {
        unsigned int lo = (unsigned int)f2bf(acc[mi][nj][0] + bias)
                        | ((unsigned int)f2bf(acc[mi][nj][1] + bias) << 16);
        unsigned int hi = (unsigned int)f2bf(acc[mi][nj][2] + bias)
                        | ((unsigned int)f2bf(acc[mi][nj][3] + bias) << 16);
        uint2 pk; pk.x = lo; pk.y = hi;
        *(uint2*)&rowp[nrow + mi * 16] = pk;
      }
    }
  }
}

// ---------------------------------------------------------------------------
// kv partials via MFMA, fragments straight from global (kvT is [dk][n] /
// [dv][n] major, so A/B b128 loads are 16 rows x 64B = fully line-coalesced;
// no LDS, no transpose needed). Per block (bh, chunk): 512 n; wave w owns
// 128 n -> one 64x64 fp32 partial into slice chunk*4+w (kv_reduce unchanged).
// A(m=dk,k=n)=kT[dk][n]; B(k=n,n=dv)=vT[dv][n]  -- same operand orientation
// as the proven GEMM (A: [m][k]-major, B: [n][k]-major).
// ---------------------------------------------------------------------------
__global__ __launch_bounds__(256)
void kv_accum_kernel(const unsigned short* __restrict__ kvT, float* __restrict__ kvpart)
{
  const int t = threadIdx.x;
  const int bh = blockIdx.x, chunk = blockIdx.y;   // (64, 16)
  const int wave = t >> 6, lane = t & 63;
  const int quad = lane >> 4, l16 = lane & 15;
  const unsigned short* kb_ = kvT + (size_t)bh * 64 * 8192;
  const unsigned short* vb_ = kvT + (size_t)(64 + bh) * 64 * 8192;
  const int n0 = chunk * 512 + wave * 128 + quad * 8;

  f4v acc[4][4];
  #pragma unroll
  for (int i = 0; i < 4; ++i)
    #pragma unroll
    for (int j = 0; j < 4; ++j) acc[i][j] = (f4v){0.f, 0.f, 0.f, 0.f};

  s8v a0[4], b0[4], a1[4], b1[4];
  #pragma unroll
  for (int mi = 0; mi < 4; ++mi) {
    a0[mi] = *(const s8v*)&kb_[(size_t)(mi * 16 + l16) * 8192 + n0];
    b0[mi] = *(const s8v*)&vb_[(size_t)(mi * 16 + l16) * 8192 + n0];
  }

#define KV_STEP(AC, BC, AN, BN, S)                                             \
  {                                                                            \
    if ((S) < 3) {                                                             \
      int nn = n0 + ((S) + 1) * 32;                                            \
      _Pragma("unroll")                                                        \
      for (int mi = 0; mi < 4; ++mi) {                                         \
        AN[mi] = *(const s8v*)&kb_[(size_t)(mi * 16 + l16) * 8192 + nn];       \
        BN[mi] = *(const s8v*)&vb_[(size_t)(mi * 16 + l16) * 8192 + nn];       \
      }                                                                        \
    }                                                                          \
    _Pragma("unroll")                                                          \
    for (int mi = 0; mi < 4; ++mi)                                             \
      _Pragma("unroll")                                                        \
      for (int nj = 0; nj < 4; ++nj)                                           \
        acc[mi][nj] = __builtin_amdgcn_mfma_f32_16x16x32_bf16(AC[mi], BC[nj],  \
                                                              acc[mi][nj], 0, 0, 0); \
  }

  KV_STEP(a0, b0, a1, b1, 0)
  KV_STEP(a1, b1, a0, b0, 1)
  KV_STEP(a0, b0, a1, b1, 2)
  KV_STEP(a1, b1, a0, b0, 3)
#undef KV_STEP

  float* dst = kvpart + ((size_t)(chunk * 4 + wave) * 64 + bh) * 4096;
  #pragma unroll
  for (int mi = 0; mi < 4; ++mi)
    #pragma unroll
    for (int nj = 0; nj < 4; ++nj)
      #pragma unroll
      for (int rr = 0; rr < 4; ++rr)
        dst[(mi * 16 + quad * 4 + rr) * 64 + nj * 16 + l16] = acc[mi][nj][rr];
}

// ---------------------------------------------------------------------------
// reduce 64 slice partials -> kvbuf[bh][4096]. grid (64 bh, 8 seg).
// ---------------------------------------------------------------------------
__global__ __launch_bounds__(256)
void kv_reduce_kernel(const float* __restrict__ kvpart, float* __restrict__ kvbuf)
{
  const int bh = blockIdx.x, seg = blockIdx.y, t = threadIdx.x;
  #pragma unroll
  for (int e = 0; e < 2; ++e) {
    int i = seg * 512 + e * 256 + t;
    float s = 0.f;
    for (int c = 0; c < 64; ++c) s += kvpart[((size_t)c * 64 + bh) * 4096 + i];
    kvbuf[(size_t)bh * 4096 + i] = s;
  }
}

// ---------------------------------------------------------------------------
// W2t[b][d][(h,k)] = sum_v (kv[b,h][k][v]*gamma[h]/||kv row||) * Wo[h*64+v][d]
// ---------------------------------------------------------------------------
__global__ __launch_bounds__(256)
void build_w2t_kernel(const float* __restrict__ kvbuf, const float* __restrict__ Wo,
                      const float* __restrict__ gamma, unsigned short* __restrict__ W2t)
{
  __shared__ float WoS[512][16];
  const int b = blockIdx.x, dt = blockIdx.y;
  const int d0 = dt * 16;
  const int t = threadIdx.x;
  for (int i = 0; i < 32; ++i) {
    int flat = i * 256 + t;
    int rr_ = flat >> 4, c = flat & 15;
    WoS[rr_][c] = Wo[(size_t)rr_ * 512 + d0 + c];
  }
  __syncthreads();
  for (int rr = 0; rr < 2; ++rr) {
    int r = rr * 256 + t;
    int h = r >> 6, k = r & 63;
    const float* krow = kvbuf + ((size_t)b * 8 + h) * 4096 + (size_t)k * 64;
    float ss = 0.f;
    #pragma unroll
    for (int v = 0; v < 64; v += 4) {
      float4 x = *(const float4*)&krow[v];
      ss += x.x * x.x + x.y * x.y + x.z * x.z + x.w * x.w;
    }
    float scale = gamma[h] * rsqrtf(ss);
    f4v accv[4];
    #pragma unroll
    for (int j = 0; j < 4; ++j) accv[j] = (f4v){0.f, 0.f, 0.f, 0.f};
    for (int v = 0; v < 64; ++v) {
      float m = krow[v] * scale;
      const float* w = &WoS[h * 64 + v][0];
      #pragma unroll
      for (int j4 = 0; j4 < 4; ++j4) {
        float4 ww = *(const float4*)&w[j4 * 4];
        accv[j4][0] = fmaf(m, ww.x, accv[j4][0]);
        accv[j4][1] = fmaf(m, ww.y, accv[j4][1]);
        accv[j4][2] = fmaf(m, ww.z, accv[j4][2]);
        accv[j4][3] = fmaf(m, ww.w, accv[j4][3]);
      }
    }
    #pragma unroll
    for (int j = 0; j < 16; ++j)
      W2t[((size_t)b * 512 + d0 + j) * 512 + r] = f2bf(accv[j >> 2][j & 3]);
  }
}

// ---------------------------------------------------------------------------
// GEMM3: Y[b] = qhat[b] @ W2t[b]^T + bo, fp32 out. Round-4 measured version
// (256x256, 4-phase); only change: A = qhat with pitch 512.
// ---------------------------------------------------------------------------
__global__ __launch_bounds__(512, 2)
void gemm_out_kernel(const unsigned short* __restrict__ qhat,
                     const unsigned short* __restrict__ W2t,
                     const float* __restrict__ bo,
                     float* __restrict__ out)
{
  __shared__ short As[2][16384];
  __shared__ short Bs[2][16384];
  const int t = threadIdx.x;
  const int o = blockIdx.x;                  // 512 blocks
  const int swz = (o & 7) * 64 + (o >> 3);   // bijective XCD swizzle
  const int nb = swz & 1, rb = swz >> 1;     // nb fast; 32 rb per XCD = 1 batch
  const int wave = t >> 6, lane = t & 63;
  const int wm = wave & 1, wn = wave >> 1;
  const int quad = lane >> 4, l16 = lane & 15;
  const int row0 = rb * 256, ncol0 = nb * 256;
  const unsigned short* Wb = W2t + (size_t)(rb >> 5) * 262144;

  const unsigned short* ap[4];
  const unsigned short* bp[4];
  int ldst[4];
  #pragma unroll
  for (int i = 0; i < 4; ++i) {
    int s = i * 512 + t;
    int m = s >> 3, kb = (s & 7) ^ (m & 7);
    ap[i] = qhat + (size_t)(row0 + m) * 512 + kb * 8;
    bp[i] = Wb + (size_t)(ncol0 + m) * 512 + kb * 8;
    ldst[i] = s * 8;
  }

  f4v acc[8][4];
  #pragma unroll
  for (int i = 0; i < 8; ++i)
    #pragma unroll
    for (int j = 0; j < 4; ++j) acc[i][j] = (f4v){0.f, 0.f, 0.f, 0.f};

  #pragma unroll
  for (int i = 0; i < 4; ++i) {
    gld16(ap[i], &As[0][ldst[i]]);
    gld16(bp[i], &Bs[0][ldst[i]]);
  }
  TILE_SYNC();

  for (int kt = 0; kt < 8; ++kt) {
    const int cur = kt & 1;
    const short* Ac = As[cur];
    const short* Bc = Bs[cur];
    short* An = (short*)As[cur ^ 1];
    short* Bn = (short*)Bs[cur ^ 1];
    const int koff = (kt + 1) * 64;
    const bool pf = kt < 7;
    s8v afr[4][2], bfr[4][2];

    // phase 0
    if (pf) {
      gld16(ap[0] + koff, &An[ldst[0]]);
      gld16(ap[1] + koff, &An[ldst[1]]);
      gld16(bp[0] + koff, &Bn[ldst[0]]);
      gld16(bp[1] + koff, &Bn[ldst[1]]);
    }
    #pragma unroll
    for (int nj = 0; nj < 4; ++nj)
      #pragma unroll
      for (int ks = 0; ks < 2; ++ks) {
        int r = wn * 64 + nj * 16 + l16;
        bfr[nj][ks] = *(const s8v*)&Bc[(r * 8 + ((ks * 4 + quad) ^ (r & 7))) * 8];
      }
    #pragma unroll
    for (int mi = 0; mi < 4; ++mi)
      #pragma unroll
      for (int ks = 0; ks < 2; ++ks) {
        int r = wm * 128 + mi * 16 + l16;
        afr[mi][ks] = *(const s8v*)&Ac[(r * 8 + ((ks * 4 + quad) ^ (r & 7))) * 8];
      }
    __builtin_amdgcn_s_setprio(1);
    #pragma unroll
    for (int mi = 0; mi < 4; ++mi)
      #pragma unroll
      for (int nj = 0; nj < 2; ++nj)
        #pragma unroll
        for (int ks = 0; ks < 2; ++ks)
          acc[mi][nj] = __builtin_amdgcn_mfma_f32_16x16x32_bf16(afr[mi][ks], bfr[nj][ks], acc[mi][nj], 0, 0, 0);
    __builtin_amdgcn_s_setprio(0);
    __builtin_amdgcn_s_barrier();

    // phase 1
    if (pf) {
      gld16(ap[2] + koff, &An[ldst[2]]);
      gld16(ap[3] + koff, &An[ldst[3]]);
      gld16(bp[2] + koff, &Bn[ldst[2]]);
      gld16(bp[3] + koff, &Bn[ldst[3]]);
    }
    __builtin_amdgcn_s_setprio(1);
    #pragma unroll
    for (int mi = 0; mi < 4; ++mi)
      #pragma unroll
      for (int nj = 2; nj < 4; ++nj)
        #pragma unroll
        for (int ks = 0; ks < 2; ++ks)
          acc[mi][nj] = __builtin_amdgcn_mfma_f32_16x16x32_bf16(afr[mi][ks], bfr[nj][ks], acc[mi][nj], 0, 0, 0);
    __builtin_amdgcn_s_setprio(0);
    __builtin_amdgcn_s_barrier();

    // phase 2
    #pragma unroll
    for (int mi = 0; mi < 4; ++mi)
      #pragma unroll
      for (int ks = 0; ks < 2; ++ks) {
        int r = wm * 128 + (4 + mi) * 16 + l16;
        afr[mi][ks] = *(const s8v*)&Ac[(r * 8 + ((ks * 4 + quad) ^ (r & 7))) * 8];
      }
    __builtin_amdgcn_s_setprio(1);
    #pragma unroll
    for (int mi = 0; mi < 4; ++mi)
      #pragma unroll
      for (int nj = 0; nj < 2; ++nj)
        #pragma unroll
        for (int ks = 0; ks < 2; ++ks)
          acc[4 + mi][nj] = __builtin_amdgcn_mfma_f32_16x16x32_bf16(afr[mi][ks], bfr[nj][ks], acc[4 + mi][nj], 0, 0, 0);
    __builtin_amdgcn_s_setprio(0);
    __builtin_amdgcn_s_barrier();

    // phase 3
    __builtin_amdgcn_s_setprio(1);
    #pragma unroll
    for (int mi = 0; mi < 4; ++mi)
      #pragma unroll
      for (int nj = 2; nj < 4; ++nj)
        #pragma unroll
        for (int ks = 0; ks < 2; ++ks)
          acc[4 + mi][nj] = __builtin_amdgcn_mfma_f32_16x16x32_bf16(afr[mi][ks], bfr[nj][ks], acc[4 + mi][nj], 0, 0, 0);
    __builtin_amdgcn_s_setprio(0);
    TILE_SYNC();
  }

  const int colbase = ncol0 + wn * 64;
  #pragma unroll
  for (int nj = 0; nj < 4; ++nj) {
    float bias = bo[colbase + nj * 16 + l16];
    #pragma unroll
    for (int mi = 0; mi < 8; ++mi)
      #pragma unroll
      for (int rr = 0; rr < 4; ++rr) {
        int row = row0 + wm * 128 + mi * 16 + quad * 4 + rr;
        int col = colbase + nj * 16 + l16;
        out[(size_t)row * 512 + col] = acc[mi][nj][rr] + bias;
      }
  }
}

// ---------------------------------------------------------------------------
extern "C" void kernel_launch(void* const* d_in, const int* in_sizes, int n_in,
                              void* d_out, int out_size, void* d_ws, size_t ws_size,
                              hipStream_t stream)
{
  (void)in_sizes; (void)n_in; (void)out_size; (void)ws_size;
  const float* X     = (const float*)d_in[0];
  const float* Wq    = (const float*)d_in[1];
  const float* bq    = (const float*)d_in[2];
  const float* Wk    = (const float*)d_in[3];
  const float* bk    = (const float*)d_in[4];
  const float* Wv    = (const float*)d_in[5];
  const float* bv    = (const float*)d_in[6];
  const float* Wo    = (const float*)d_in[7];
  const float* bo    = (const float*)d_in[8];
  const float* gamma = (const float*)d_in[9];

  char* ws = (char*)d_ws;
  unsigned short* qhat = (unsigned short*)ws;                        // 67108864 B
  unsigned short* kvT  = (unsigned short*)(ws + 67108864);           // 134217728 B
  unsigned short* Xbf  = (unsigned short*)(ws + 201326592);          // 67108864 B
  float* kvpart = (float*)(ws + 201326592);                          // aliases Xbf (dead after gemm1): 64 MiB
  unsigned short* Wt  = (unsigned short*)(ws + 201326592 + 67108864);          // 1572864 B
  float* kvbuf        = (float*)(ws + 201326592 + 67108864 + 1572864);         // 1048576 B
  unsigned short* W2t = (unsigned short*)(ws + 201326592 + 67108864 + 1572864 + 1048576); // 4194304 B

  dim3 blk(256);
  convert_x_kernel<<<16384, blk, 0, stream>>>(X, Xbf);
  transpose_w_kernel<<<dim3(8, 24), blk, 0, stream>>>(Wq, Wk, Wv, Wt);
  gemm_qkv_kernel<<<dim3(12, 512), blk, 0, stream>>>(Xbf, Wt, bq, bk, bv, gamma, qhat, kvT);
  kv_accum_kernel<<<dim3(64, 16), blk, 0, stream>>>(kvT, kvpart);
  kv_reduce_kernel<<<dim3(64, 8), blk, 0, stream>>>(kvpart, kvbuf);
  build_w2t_kernel<<<dim3(8, 32), blk, 0, stream>>>(kvbuf, Wo, gamma, W2t);
  gemm_out_kernel<<<512, dim3(512), 0, stream>>>(qhat, W2t, bo, (float*)d_out);
}